// Round 2
// baseline (380.483 us; speedup 1.0000x reference)
//
#include <hip/hip_runtime.h>

#define N3   (64*64*64)      // 262144
#define NO   70
#define NO2  (NO*NO)
#define NO3  (NO*NO*NO)      // 343000
#define OH   (2*NO3)         // 686000  (h output elements)
#define SZ   (2*16*N3)       // 8388608 (each [B,16,D,H,W] output)

typedef __attribute__((ext_vector_type(4))) float f4;

__device__ __forceinline__ float relu(float x){ return x > 0.f ? x : 0.f; }

// ---------------- interior: one thread = 4 consecutive-w voxels of the 64^3 grid ----
__global__ __launch_bounds__(256) void ham_interior(
    const float* __restrict__ p, const float* __restrict__ q,
    const float* __restrict__ W1, const float* __restrict__ b1,
    const float* __restrict__ W2, const float* __restrict__ b2,
    const float* __restrict__ W3, const float* __restrict__ b3p,
    float* __restrict__ out)
{
    __shared__ float WpT[16][16];   // W1[:,0:16]^T  -> [c][o]
    __shared__ float WqT[16][16];   // W1[:,48:64]^T -> [c][o]
    __shared__ float W2l[16][16];   // W2[o][c]
    __shared__ float b1l[16], b2l[16], W3l[16];
    __shared__ float s1x[16], s1y[16], s2x[16], s2y[16];

    int t = threadIdx.x;
    {
        int o = t >> 4, c = t & 15;
        WpT[c][o] = W1[o*96 + c];
        WqT[c][o] = W1[o*96 + 48 + c];
        W2l[o][c] = W2[o*16 + c];
    }
    if (t < 16) {
        b1l[t] = b1[t]; b2l[t] = b2[t]; W3l[t] = W3[t];
        float ax=0.f, ay=0.f, bx=0.f, by=0.f;
        #pragma unroll
        for (int j = 0; j < 16; ++j) {
            ax += W1[t*96 + 16 + j];
            ay += W1[t*96 + 32 + j];
            bx += W1[t*96 + 64 + j];
            by += W1[t*96 + 80 + j];
        }
        s1x[t]=ax; s1y[t]=ay; s2x[t]=bx; s2y[t]=by;
    }
    __syncthreads();

    int i  = blockIdx.x * 256 + t;      // 131072 threads total
    int w4 = i & 15;  int w0 = w4 << 2; // w0 in {0,4,...,60}
    int r  = i >> 4;
    int h0 = r & 63;  r >>= 6;
    int d0 = r & 63;  int b = r >> 6;

    float b3v = b3p[0];

    const float* ps = p + (b*16 + 1)*N3;
    const float* qs = q + (b*16 + 1)*N3;

    // load 6 floats s[w0-1 .. w0+4] of slice row (dd,hh), zero-padded
    auto row6 = [&](const float* s, int dd, int hh, float rr[6]) {
        if ((unsigned)dd >= 64u || (unsigned)hh >= 64u) {
            #pragma unroll
            for (int j = 0; j < 6; ++j) rr[j] = 0.f;
            return;
        }
        const float* rp = s + dd*4096 + hh*64 + w0;
        f4 v = *(const f4*)rp;          // 16B aligned (w0 % 4 == 0)
        rr[1]=v[0]; rr[2]=v[1]; rr[3]=v[2]; rr[4]=v[3];
        rr[0] = (w4 > 0)  ? rp[-1] : 0.f;
        rr[5] = (w4 < 15) ? rp[4]  : 0.f;
    };

    float dpx[4], dpy[4], dqx[4], dqy[4];
    {
        float rc[6], ra[6], rb[6], gc[4];
        row6(ps, d0,   h0,   rc);
        row6(ps, d0-1, h0,   ra);
        row6(ps, d0+1, h0,   rb);
        #pragma unroll
        for (int j = 0; j < 4; ++j) gc[j]  = 0.5f*(rc[j+2]-rc[j]);
        #pragma unroll
        for (int j = 0; j < 4; ++j) dpx[j] = 0.5f*(ra[j+2]-ra[j]) + gc[j] + 0.5f*(rb[j+2]-rb[j]);
        row6(ps, d0, h0-1, ra);
        row6(ps, d0, h0+1, rb);
        #pragma unroll
        for (int j = 0; j < 4; ++j) dpy[j] = 0.5f*(ra[j+2]-ra[j]) + gc[j] + 0.5f*(rb[j+2]-rb[j]);

        row6(qs, d0,   h0,   rc);
        row6(qs, d0-1, h0,   ra);
        row6(qs, d0+1, h0,   rb);
        #pragma unroll
        for (int j = 0; j < 4; ++j) gc[j]  = 0.5f*(rc[j+2]-rc[j]);
        #pragma unroll
        for (int j = 0; j < 4; ++j) dqx[j] = 0.5f*(ra[j+2]-ra[j]) + gc[j] + 0.5f*(rb[j+2]-rb[j]);
        row6(qs, d0, h0-1, ra);
        row6(qs, d0, h0+1, rb);
        #pragma unroll
        for (int j = 0; j < 4; ++j) dqy[j] = 0.5f*(ra[j+2]-ra[j]) + gc[j] + 0.5f*(rb[j+2]-rb[j]);
    }

    float y1[4][16];
    #pragma unroll
    for (int j = 0; j < 4; ++j)
        #pragma unroll
        for (int o = 0; o < 16; ++o)
            y1[j][o] = b1l[o] + s1x[o]*dpx[j] + s1y[o]*dpy[j]
                              + s2x[o]*dqx[j] + s2y[o]*dqy[j];

    int ibase = b*16*N3 + d0*4096 + h0*64 + w0;

    float* outp  = out + OH;
    float* outdx = out + OH + SZ;
    float* outdy = out + OH + 2*SZ;
    float* outq  = out + OH + 3*SZ;
    float* outqx = out + OH + 4*SZ;
    float* outqy = out + OH + 5*SZ;

    #pragma unroll
    for (int c = 0; c < 16; ++c) {
        f4 pc = *(const f4*)(p + ibase + c*N3);
        f4 qc = *(const f4*)(q + ibase + c*N3);
        __builtin_nontemporal_store(pc, (f4*)(outp + ibase + c*N3));
        __builtin_nontemporal_store(qc, (f4*)(outq + ibase + c*N3));
        #pragma unroll
        for (int o = 0; o < 16; ++o) {
            float wp = WpT[c][o], wq = WqT[c][o];
            #pragma unroll
            for (int j = 0; j < 4; ++j)
                y1[j][o] += wp*pc[j] + wq*qc[j];
        }
    }

    f4 vdx, vdy, vqx, vqy;
    #pragma unroll
    for (int j = 0; j < 4; ++j) { vdx[j]=dpx[j]; vdy[j]=dpy[j]; vqx[j]=dqx[j]; vqy[j]=dqy[j]; }
    #pragma unroll
    for (int c = 0; c < 16; ++c) {
        __builtin_nontemporal_store(vdx, (f4*)(outdx + ibase + c*N3));
        __builtin_nontemporal_store(vdy, (f4*)(outdy + ibase + c*N3));
        __builtin_nontemporal_store(vqx, (f4*)(outqx + ibase + c*N3));
        __builtin_nontemporal_store(vqy, (f4*)(outqy + ibase + c*N3));
    }

    // layers 2,3 per voxel; h goes to the 70^3 grid at (+3,+3,+3)
    int obase = b*NO3 + (d0+3)*NO2 + (h0+3)*NO + (w0+3);
    #pragma unroll
    for (int j = 0; j < 4; ++j) {
        float acc = b3v;
        #pragma unroll
        for (int o = 0; o < 16; ++o) {
            float a2 = b2l[o];
            #pragma unroll
            for (int c = 0; c < 16; ++c) a2 += W2l[o][c]*relu(y1[j][c]);
            acc += W3l[o]*relu(a2);
        }
        out[obase + j] = relu(acc);
    }
}

// ---------------- border: the three constant shells of h --------------------------
__global__ __launch_bounds__(256) void ham_border(
    const float* __restrict__ b1, const float* __restrict__ W2,
    const float* __restrict__ b2, const float* __restrict__ W3,
    const float* __restrict__ b3p, float* __restrict__ out)
{
    int i = blockIdx.x * 256 + threadIdx.x;
    if (i >= OH) return;

    int b = i / NO3;
    int r = i - b*NO3;
    int d = r / NO2; r -= d*NO2;
    int h = r / NO;
    int w = r - h*NO;
    (void)b;

    // interior handled by ham_interior
    if ((unsigned)(d-3) < 64u && (unsigned)(h-3) < 64u && (unsigned)(w-3) < 64u) return;

    float b3v = b3p[0];
    float val;
    if ((unsigned)(d-1) >= 68u || (unsigned)(h-1) >= 68u || (unsigned)(w-1) >= 68u) {
        val = relu(b3v);
    } else if ((unsigned)(d-2) >= 66u || (unsigned)(h-2) >= 66u || (unsigned)(w-2) >= 66u) {
        float acc = b3v;
        #pragma unroll
        for (int o = 0; o < 16; ++o) acc += W3[o]*relu(b2[o]);
        val = relu(acc);
    } else {
        float acc = b3v;
        #pragma unroll
        for (int o = 0; o < 16; ++o) {
            float a2 = b2[o];
            #pragma unroll
            for (int c = 0; c < 16; ++c) a2 += W2[o*16 + c]*relu(b1[c]);
            acc += W3[o]*relu(a2);
        }
        val = relu(acc);
    }
    out[i] = val;
}

extern "C" void kernel_launch(void* const* d_in, const int* in_sizes, int n_in,
                              void* d_out, int out_size, void* d_ws, size_t ws_size,
                              hipStream_t stream) {
    const float* p  = (const float*)d_in[0];
    const float* q  = (const float*)d_in[1];
    const float* W1 = (const float*)d_in[2];
    const float* b1 = (const float*)d_in[3];
    const float* W2 = (const float*)d_in[4];
    const float* b2 = (const float*)d_in[5];
    const float* W3 = (const float*)d_in[6];
    const float* b3 = (const float*)d_in[7];
    float* out = (float*)d_out;

    // interior: 2 * 64 * 64 * 16 threads = 131072 -> 512 blocks
    ham_interior<<<512, 256, 0, stream>>>(p, q, W1, b1, W2, b2, W3, b3, out);
    // border shells of h
    ham_border<<<(OH + 255)/256, 256, 0, stream>>>(b1, W2, b2, W3, b3, out);
}